// Round 21
// baseline (115.593 us; speedup 1.0000x reference)
//
#include <hip/hip_runtime.h>
#include <hip/hip_bf16.h>
#include <stdint.h>

#define S_LEN 4096
#define DK    64

typedef __bf16 bf16x8  __attribute__((ext_vector_type(8)));
typedef float  f32x16  __attribute__((ext_vector_type(16)));

__device__ __forceinline__ short f2bf(float f) {
    union { __bf16 h; short s; } u; u.h = (__bf16)f; return u.s;
}

__device__ __forceinline__ uint32_t cvtpk_bf16(float lo, float hi) {
    uint32_t d;
    asm("v_cvt_pk_bf16_f32 %0, %1, %2" : "=&v"(d) : "v"(lo), "v"(hi));
    return d;
}
__device__ __forceinline__ void plswap(uint32_t& a, uint32_t& b) {
    asm("v_permlane32_swap_b32 %0, %1" : "+v"(a), "+v"(b));
}

// ---- prep: fragment-major bf16 layout so a wave's MFMA fragment load is one
// fully-coalesced 1KB global read.
//   K element (row, col=16s+8h+e)  -> WK[((b*64+t)*4+s)*1024 + (row*2+h)*8 + e]
//   V^T element (d, key=16s+8h+e)  -> WV[((b*64+t)*4+s)*1024 + (d*2+h)*8 + e]
__global__ __launch_bounds__(256) void prep_kernel(
    const float* __restrict__ K, const float* __restrict__ V,
    short* __restrict__ WK, short* __restrict__ WV)
{
    const int t = blockIdx.x, b = blockIdx.y;
    const int tid = threadIdx.x;
    const size_t ibase = ((size_t)b * S_LEN + (size_t)t * 64) * DK;
    const size_t obase = ((size_t)b * 64 + t) * 4096;
    const int r0 = tid >> 4;          // 0..15
    const int c0 = (tid & 15) * 4;    // 0..60

    {
        const int s = c0 >> 4, h = (c0 >> 3) & 1, e = c0 & 7;
        #pragma unroll
        for (int i = 0; i < 4; ++i) {
            const int row = r0 + 16 * i;
            const float4 f = *reinterpret_cast<const float4*>(K + ibase + (size_t)row * DK + c0);
            short4 sp;
            sp.x = f2bf(f.x); sp.y = f2bf(f.y); sp.z = f2bf(f.z); sp.w = f2bf(f.w);
            *reinterpret_cast<short4*>(WK + obase + (size_t)s * 1024 + (row * 2 + h) * 8 + e) = sp;
        }
    }
    {
        float4 vf[4];
        #pragma unroll
        for (int j = 0; j < 4; ++j)
            vf[j] = *reinterpret_cast<const float4*>(V + ibase + (size_t)(4 * r0 + j) * DK + c0);
        const int sk = r0 >> 2, hk = (r0 >> 1) & 1, ek = (r0 & 1) * 4;
        #pragma unroll
        for (int jj = 0; jj < 4; ++jj) {
            const int d = c0 + jj;
            short4 sp;
            sp.x = f2bf(reinterpret_cast<const float*>(&vf[0])[jj]);
            sp.y = f2bf(reinterpret_cast<const float*>(&vf[1])[jj]);
            sp.z = f2bf(reinterpret_cast<const float*>(&vf[2])[jj]);
            sp.w = f2bf(reinterpret_cast<const float*>(&vf[3])[jj]);
            *reinterpret_cast<short4*>(WV + obase + (size_t)sk * 1024 + (d * 2 + hk) * 8 + ek) = sp;
        }
    }
}

// ---- main: streaming flash attention with 4-way key-segment split.
// 1024 blocks x 256 threads. Block (x,y): qb = 63-x, batch = y>>1, qsub = y&1
// (big blocks dispatch first). The block owns 32 q-rows; its 4 waves stream
// DISJOINT contiguous key-tile segments with ZERO synchronization (no LDS in
// the loop, fragments straight from the fragment-major ws, L2-resident),
// then one barrier + 4-way flash merge in LDS. 4096 waves total.
__global__ __launch_bounds__(256, 4) void attn_kernel(
    const float* __restrict__ Q, float* __restrict__ O,
    const short* __restrict__ WK, const short* __restrict__ WV)
{
    __shared__ float  Op[4][2048];    // per-wave O-partial [row][d], f32
    __shared__ float2 Mlw[4][32];     // per-wave {m,l} per row (log2 domain)

    const int tid  = threadIdx.x;
    const int wave = tid >> 6;
    const int lane = tid & 63;
    const int q32  = lane & 31;
    const int hi   = lane >> 5;
    const int hi4  = hi * 4;
    const int hi8  = hi * 8;

    const int qb    = 63 - (int)blockIdx.x;
    const int batch = (int)blockIdx.y >> 1;
    const int qsub  = blockIdx.y & 1;
    const size_t bo = (size_t)batch * S_LEN * DK;
    const short* WKb = WK + (size_t)batch * 262144;
    const short* WVb = WV + (size_t)batch * 262144;

    const int q0   = qb * 64;
    const int qrow = q0 + 32 * qsub + q32;   // this lane's softmax row
    const int idx8 = (q32 * 2 + hi) * 8;     // fragment-major lane offset (shorts)

    const int ntiles = qb + 1;
    const int kt0 = (wave * ntiles) >> 2;        // this wave's segment
    const int kt1 = ((wave + 1) * ntiles) >> 2;

    const float NEG_INF = -__builtin_inff();
    const float MFLOOR  = -1e38f;
    const float QSCALE  = 0.015625f * 1.44269504088896341f;  // 1/64 * log2(e)
    const float THR     = 8.0f;

    // Q fragments (B operand), scale folded
    bf16x8 qf[4];
    {
        const float* Qr = Q + bo + (size_t)qrow * DK;
        #pragma unroll
        for (int s = 0; s < 4; ++s) {
            const float4 a = *reinterpret_cast<const float4*>(Qr + 16 * s + hi8);
            const float4 b = *reinterpret_cast<const float4*>(Qr + 16 * s + hi8 + 4);
            qf[s][0] = (__bf16)(a.x * QSCALE); qf[s][1] = (__bf16)(a.y * QSCALE);
            qf[s][2] = (__bf16)(a.z * QSCALE); qf[s][3] = (__bf16)(a.w * QSCALE);
            qf[s][4] = (__bf16)(b.x * QSCALE); qf[s][5] = (__bf16)(b.y * QSCALE);
            qf[s][6] = (__bf16)(b.z * QSCALE); qf[s][7] = (__bf16)(b.w * QSCALE);
        }
    }

    float m_run = MFLOOR, l_run = 0.f;
    f32x16 oa0, oa1;  // O-partial[q=crow(r,hi)][d = q32 / 32+q32]
    #pragma unroll
    for (int r = 0; r < 16; ++r) { oa0[r] = 0.f; oa1[r] = 0.f; }

    for (int kt = kt0; kt < kt1; ++kt) {
        const short* Kt = WKb + (size_t)kt * 4096;
        const short* Vt = WVb + (size_t)kt * 4096;

        // 16 coalesced fragment loads; compiler overlaps V arrival with QK^T.
        bf16x8 kf0[4], kf1[4], vf0[4], vf1[4];
        #pragma unroll
        for (int s = 0; s < 4; ++s) {
            kf0[s] = *reinterpret_cast<const bf16x8*>(Kt + s * 1024 + idx8);
            kf1[s] = *reinterpret_cast<const bf16x8*>(Kt + s * 1024 + 512 + idx8);
        }
        #pragma unroll
        for (int s = 0; s < 4; ++s) {
            vf0[s] = *reinterpret_cast<const bf16x8*>(Vt + s * 1024 + idx8);
            vf1[s] = *reinterpret_cast<const bf16x8*>(Vt + s * 1024 + 512 + idx8);
        }

        // ---- S^T = K Q (swapped): lane owns full row q32
        f32x16 sa0, sa1;
        #pragma unroll
        for (int r = 0; r < 16; ++r) { sa0[r] = 0.f; sa1[r] = 0.f; }
        __builtin_amdgcn_s_setprio(1);
        #pragma unroll
        for (int s = 0; s < 4; ++s) {
            sa0 = __builtin_amdgcn_mfma_f32_32x32x16_bf16(kf0[s], qf[s], sa0, 0, 0, 0);
            sa1 = __builtin_amdgcn_mfma_f32_32x32x16_bf16(kf1[s], qf[s], sa1, 0, 0, 0);
        }
        __builtin_amdgcn_s_setprio(0);

        // ---- causal mask (diag tile only; uniform branch) + row max
        float ma[4] = {NEG_INF, NEG_INF, NEG_INF, NEG_INF};
        if (kt == qb) {
            const int keybase = kt * 64 + hi4;
            #pragma unroll
            for (int r = 0; r < 16; ++r) {
                const int kl = (r & 3) + 8 * (r >> 2);
                if (keybase + kl > qrow) sa0[r] = NEG_INF;
                ma[r & 3] = fmaxf(ma[r & 3], sa0[r]);
                if (keybase + kl + 32 > qrow) sa1[r] = NEG_INF;
                ma[r & 3] = fmaxf(ma[r & 3], sa1[r]);
            }
        } else {
            #pragma unroll
            for (int r = 0; r < 16; ++r) {
                ma[r & 3] = fmaxf(ma[r & 3], sa0[r]);
                ma[r & 3] = fmaxf(ma[r & 3], sa1[r]);
            }
        }
        float mt = fmaxf(fmaxf(ma[0], ma[1]), fmaxf(ma[2], ma[3]));
        mt = fmaxf(mt, __shfl_xor(mt, 32));

        // ---- T13: rescale only when max grew past THR (first tile fires;
        // alpha underflows to 0 from MFLOOR, establishing finite m_run)
        if (!__all(mt <= m_run + THR)) {
            const float mnew = fmaxf(m_run, mt);
            const float alpha = __builtin_amdgcn_exp2f(m_run - mnew);
            m_run = mnew;
            l_run *= alpha;
            #pragma unroll
            for (int r = 0; r < 16; ++r) {
                const float ar = __shfl(alpha, (r & 3) + 8 * (r >> 2) + hi4);
                oa0[r] *= ar; oa1[r] *= ar;
            }
        }

        // ---- exp2 + row sum (4-way partials); P bounded by 2^THR
        float pp[4] = {0.f, 0.f, 0.f, 0.f};
        #pragma unroll
        for (int r = 0; r < 16; ++r) {
            sa0[r] = __builtin_amdgcn_exp2f(sa0[r] - m_run); pp[r & 3] += sa0[r];
            sa1[r] = __builtin_amdgcn_exp2f(sa1[r] - m_run); pp[r & 3] += sa1[r];
        }
        float ps = (pp[0] + pp[1]) + (pp[2] + pp[3]);
        ps += __shfl_xor(ps, 32);
        l_run += ps;

        // ---- PV with in-register P (T12)
        __builtin_amdgcn_s_setprio(1);
        #pragma unroll
        for (int c = 0; c < 2; ++c) {
            const f32x16& sp = c ? sa1 : sa0;
            #pragma unroll
            for (int s2 = 0; s2 < 2; ++s2) {
                uint32_t a0 = cvtpk_bf16(sp[8*s2+0], sp[8*s2+1]);
                uint32_t a1 = cvtpk_bf16(sp[8*s2+2], sp[8*s2+3]);
                uint32_t b0 = cvtpk_bf16(sp[8*s2+4], sp[8*s2+5]);
                uint32_t b1 = cvtpk_bf16(sp[8*s2+6], sp[8*s2+7]);
                plswap(a0, b0);
                plswap(a1, b1);
                union { uint32_t u[4]; bf16x8 v; } pw;
                pw.u[0] = a0; pw.u[1] = a1; pw.u[2] = b0; pw.u[3] = b1;
                oa0 = __builtin_amdgcn_mfma_f32_32x32x16_bf16(pw.v, vf0[2*c+s2], oa0, 0, 0, 0);
                oa1 = __builtin_amdgcn_mfma_f32_32x32x16_bf16(pw.v, vf1[2*c+s2], oa1, 0, 0, 0);
            }
        }
        __builtin_amdgcn_s_setprio(0);
    }

    // ---- dump partials to LDS (write banks: col%32 distinct, 2-way free)
    {
        float* Ow = &Op[wave][0];
        #pragma unroll
        for (int r = 0; r < 16; ++r) {
            const int row = (r & 3) + 8 * (r >> 2) + hi4;
            Ow[row * 64 + q32]      = oa0[r];
            Ow[row * 64 + 32 + q32] = oa1[r];
        }
        if (hi == 0) Mlw[wave][q32] = make_float2(m_run, l_run);
    }
    __syncthreads();

    // ---- 4-way flash merge: wave w handles rows 8w..8w+7; lane = col
    {
        float* Ob = O + bo + (size_t)(q0 + 32 * qsub) * DK;
        #pragma unroll
        for (int rl = 0; rl < 8; ++rl) {
            const int row = 8 * wave + rl;
            float mg[4], lg[4];
            #pragma unroll
            for (int g = 0; g < 4; ++g) {
                const float2 v = Mlw[g][row];
                mg[g] = v.x; lg[g] = v.y;
            }
            const float mtot = fmaxf(fmaxf(mg[0], mg[1]), fmaxf(mg[2], mg[3]));
            float eg[4], ltot = 0.f;
            #pragma unroll
            for (int g = 0; g < 4; ++g) {
                eg[g] = __builtin_amdgcn_exp2f(mg[g] - mtot);  // MFLOOR -> 0
                ltot += eg[g] * lg[g];
            }
            const float inv = (ltot > 0.f) ? (1.0f / ltot) : 0.f;
            float acc = 0.f;
            #pragma unroll
            for (int g = 0; g < 4; ++g)
                acc += eg[g] * Op[g][row * 64 + lane];
            Ob[(size_t)row * DK + lane] = acc * inv;   // 256B coalesced per row
        }
    }
}

extern "C" void kernel_launch(void* const* d_in, const int* in_sizes, int n_in,
                              void* d_out, int out_size, void* d_ws, size_t ws_size,
                              hipStream_t stream) {
    (void)in_sizes; (void)n_in; (void)out_size; (void)ws_size;
    const float* q = (const float*)d_in[0];
    const float* k = (const float*)d_in[1];
    const float* v = (const float*)d_in[2];
    float* o = (float*)d_out;
    short* wk = (short*)d_ws;                       // 4 MB bf16 K fragments
    short* wv = wk + (size_t)8 * 64 * 4096;         // 4 MB bf16 V^T fragments

    hipLaunchKernelGGL(prep_kernel, dim3(64, 8), dim3(256), 0, stream, k, v, wk, wv);
    hipLaunchKernelGGL(attn_kernel, dim3(64, 16), dim3(256), 0, stream, q, o, wk, wv);
}

// Round 22
// 55.444 us; speedup vs baseline: 2.0848x; 2.0848x over previous
//
#include <hip/hip_runtime.h>
#include <hip/hip_bf16.h>
#include <stdint.h>

#define S_LEN 4096
#define DK    64

typedef __bf16 bf16x8  __attribute__((ext_vector_type(8)));
typedef float  f32x16  __attribute__((ext_vector_type(16)));

__device__ __forceinline__ short f2bf(float f) {
    union { __bf16 h; short s; } u; u.h = (__bf16)f; return u.s;
}

__device__ __forceinline__ uint32_t cvtpk_bf16(float lo, float hi) {
    uint32_t d;
    asm("v_cvt_pk_bf16_f32 %0, %1, %2" : "=&v"(d) : "v"(lo), "v"(hi));
    return d;
}
__device__ __forceinline__ void plswap(uint32_t& a, uint32_t& b) {
    asm("v_permlane32_swap_b32 %0, %1" : "+v"(a), "+v"(b));
}

// ---- prep: fragment-major bf16 layout so a wave's MFMA fragment load is one
// fully-coalesced 1KB global read.
//   K element (row, col=16s+8h+e)  -> WK[((b*64+t)*4+s)*1024 + (row*2+h)*8 + e]
//   V^T element (d, key=16s+8h+e)  -> WV[((b*64+t)*4+s)*1024 + (d*2+h)*8 + e]
__global__ __launch_bounds__(256) void prep_kernel(
    const float* __restrict__ K, const float* __restrict__ V,
    short* __restrict__ WK, short* __restrict__ WV)
{
    const int t = blockIdx.x, b = blockIdx.y;
    const int tid = threadIdx.x;
    const size_t ibase = ((size_t)b * S_LEN + (size_t)t * 64) * DK;
    const size_t obase = ((size_t)b * 64 + t) * 4096;
    const int r0 = tid >> 4;          // 0..15
    const int c0 = (tid & 15) * 4;    // 0..60

    {
        const int s = c0 >> 4, h = (c0 >> 3) & 1, e = c0 & 7;
        #pragma unroll
        for (int i = 0; i < 4; ++i) {
            const int row = r0 + 16 * i;
            const float4 f = *reinterpret_cast<const float4*>(K + ibase + (size_t)row * DK + c0);
            short4 sp;
            sp.x = f2bf(f.x); sp.y = f2bf(f.y); sp.z = f2bf(f.z); sp.w = f2bf(f.w);
            *reinterpret_cast<short4*>(WK + obase + (size_t)s * 1024 + (row * 2 + h) * 8 + e) = sp;
        }
    }
    {
        float4 vf[4];
        #pragma unroll
        for (int j = 0; j < 4; ++j)
            vf[j] = *reinterpret_cast<const float4*>(V + ibase + (size_t)(4 * r0 + j) * DK + c0);
        const int sk = r0 >> 2, hk = (r0 >> 1) & 1, ek = (r0 & 1) * 4;
        #pragma unroll
        for (int jj = 0; jj < 4; ++jj) {
            const int d = c0 + jj;
            short4 sp;
            sp.x = f2bf(reinterpret_cast<const float*>(&vf[0])[jj]);
            sp.y = f2bf(reinterpret_cast<const float*>(&vf[1])[jj]);
            sp.z = f2bf(reinterpret_cast<const float*>(&vf[2])[jj]);
            sp.w = f2bf(reinterpret_cast<const float*>(&vf[3])[jj]);
            *reinterpret_cast<short4*>(WV + obase + (size_t)sk * 1024 + (d * 2 + hk) * 8 + ek) = sp;
        }
    }
}

// ---- main: streaming flash attention with 4-way key-segment split.
// 1024 blocks x 256 threads. Block (x,y): qb = 63-x, batch = y>>1, qsub = y&1
// (big blocks dispatch first). The block owns 32 q-rows; its 4 waves stream
// DISJOINT contiguous key-tile segments with ZERO synchronization (no LDS in
// the loop, fragments straight from the fragment-major ws, L2-resident),
// then one barrier + 4-way flash merge in LDS. 4096 waves total.
// __launch_bounds__ 2nd arg MUST be 2: arg=4 drove the allocator to a
// 64-VGPR budget -> ~80 regs spilled -> 72MB scratch writes (R21: 115us).
// LDS (33.8KB) already yields the desired 4 blocks/CU; no reg cap needed.
__global__ __launch_bounds__(256, 2) void attn_kernel(
    const float* __restrict__ Q, float* __restrict__ O,
    const short* __restrict__ WK, const short* __restrict__ WV)
{
    __shared__ float  Op[4][2048];    // per-wave O-partial [row][d], f32
    __shared__ float2 Mlw[4][32];     // per-wave {m,l} per row (log2 domain)

    const int tid  = threadIdx.x;
    const int wave = tid >> 6;
    const int lane = tid & 63;
    const int q32  = lane & 31;
    const int hi   = lane >> 5;
    const int hi4  = hi * 4;
    const int hi8  = hi * 8;

    const int qb    = 63 - (int)blockIdx.x;
    const int batch = (int)blockIdx.y >> 1;
    const int qsub  = blockIdx.y & 1;
    const size_t bo = (size_t)batch * S_LEN * DK;
    const short* WKb = WK + (size_t)batch * 262144;
    const short* WVb = WV + (size_t)batch * 262144;

    const int q0   = qb * 64;
    const int qrow = q0 + 32 * qsub + q32;   // this lane's softmax row
    const int idx8 = (q32 * 2 + hi) * 8;     // fragment-major lane offset (shorts)

    const int ntiles = qb + 1;
    const int kt0 = (wave * ntiles) >> 2;        // this wave's segment
    const int kt1 = ((wave + 1) * ntiles) >> 2;

    const float NEG_INF = -__builtin_inff();
    const float MFLOOR  = -1e38f;
    const float QSCALE  = 0.015625f * 1.44269504088896341f;  // 1/64 * log2(e)
    const float THR     = 8.0f;

    // Q fragments (B operand), scale folded
    bf16x8 qf[4];
    {
        const float* Qr = Q + bo + (size_t)qrow * DK;
        #pragma unroll
        for (int s = 0; s < 4; ++s) {
            const float4 a = *reinterpret_cast<const float4*>(Qr + 16 * s + hi8);
            const float4 b = *reinterpret_cast<const float4*>(Qr + 16 * s + hi8 + 4);
            qf[s][0] = (__bf16)(a.x * QSCALE); qf[s][1] = (__bf16)(a.y * QSCALE);
            qf[s][2] = (__bf16)(a.z * QSCALE); qf[s][3] = (__bf16)(a.w * QSCALE);
            qf[s][4] = (__bf16)(b.x * QSCALE); qf[s][5] = (__bf16)(b.y * QSCALE);
            qf[s][6] = (__bf16)(b.z * QSCALE); qf[s][7] = (__bf16)(b.w * QSCALE);
        }
    }

    float m_run = MFLOOR, l_run = 0.f;
    f32x16 oa0, oa1;  // O-partial[q=crow(r,hi)][d = q32 / 32+q32]
    #pragma unroll
    for (int r = 0; r < 16; ++r) { oa0[r] = 0.f; oa1[r] = 0.f; }

    for (int kt = kt0; kt < kt1; ++kt) {
        const short* Kt = WKb + (size_t)kt * 4096;
        const short* Vt = WVb + (size_t)kt * 4096;

        // 16 coalesced fragment loads; compiler overlaps V arrival with QK^T.
        bf16x8 kf0[4], kf1[4], vf0[4], vf1[4];
        #pragma unroll
        for (int s = 0; s < 4; ++s) {
            kf0[s] = *reinterpret_cast<const bf16x8*>(Kt + s * 1024 + idx8);
            kf1[s] = *reinterpret_cast<const bf16x8*>(Kt + s * 1024 + 512 + idx8);
        }
        #pragma unroll
        for (int s = 0; s < 4; ++s) {
            vf0[s] = *reinterpret_cast<const bf16x8*>(Vt + s * 1024 + idx8);
            vf1[s] = *reinterpret_cast<const bf16x8*>(Vt + s * 1024 + 512 + idx8);
        }

        // ---- S^T = K Q (swapped): lane owns full row q32
        f32x16 sa0, sa1;
        #pragma unroll
        for (int r = 0; r < 16; ++r) { sa0[r] = 0.f; sa1[r] = 0.f; }
        __builtin_amdgcn_s_setprio(1);
        #pragma unroll
        for (int s = 0; s < 4; ++s) {
            sa0 = __builtin_amdgcn_mfma_f32_32x32x16_bf16(kf0[s], qf[s], sa0, 0, 0, 0);
            sa1 = __builtin_amdgcn_mfma_f32_32x32x16_bf16(kf1[s], qf[s], sa1, 0, 0, 0);
        }
        __builtin_amdgcn_s_setprio(0);

        // ---- causal mask (diag tile only; uniform branch) + row max
        float ma[4] = {NEG_INF, NEG_INF, NEG_INF, NEG_INF};
        if (kt == qb) {
            const int keybase = kt * 64 + hi4;
            #pragma unroll
            for (int r = 0; r < 16; ++r) {
                const int kl = (r & 3) + 8 * (r >> 2);
                if (keybase + kl > qrow) sa0[r] = NEG_INF;
                ma[r & 3] = fmaxf(ma[r & 3], sa0[r]);
                if (keybase + kl + 32 > qrow) sa1[r] = NEG_INF;
                ma[r & 3] = fmaxf(ma[r & 3], sa1[r]);
            }
        } else {
            #pragma unroll
            for (int r = 0; r < 16; ++r) {
                ma[r & 3] = fmaxf(ma[r & 3], sa0[r]);
                ma[r & 3] = fmaxf(ma[r & 3], sa1[r]);
            }
        }
        float mt = fmaxf(fmaxf(ma[0], ma[1]), fmaxf(ma[2], ma[3]));
        mt = fmaxf(mt, __shfl_xor(mt, 32));

        // ---- T13: rescale only when max grew past THR (first tile fires;
        // alpha underflows to 0 from MFLOOR, establishing finite m_run)
        if (!__all(mt <= m_run + THR)) {
            const float mnew = fmaxf(m_run, mt);
            const float alpha = __builtin_amdgcn_exp2f(m_run - mnew);
            m_run = mnew;
            l_run *= alpha;
            #pragma unroll
            for (int r = 0; r < 16; ++r) {
                const float ar = __shfl(alpha, (r & 3) + 8 * (r >> 2) + hi4);
                oa0[r] *= ar; oa1[r] *= ar;
            }
        }

        // ---- exp2 + row sum (4-way partials); P bounded by 2^THR
        float pp[4] = {0.f, 0.f, 0.f, 0.f};
        #pragma unroll
        for (int r = 0; r < 16; ++r) {
            sa0[r] = __builtin_amdgcn_exp2f(sa0[r] - m_run); pp[r & 3] += sa0[r];
            sa1[r] = __builtin_amdgcn_exp2f(sa1[r] - m_run); pp[r & 3] += sa1[r];
        }
        float ps = (pp[0] + pp[1]) + (pp[2] + pp[3]);
        ps += __shfl_xor(ps, 32);
        l_run += ps;

        // ---- PV with in-register P (T12)
        __builtin_amdgcn_s_setprio(1);
        #pragma unroll
        for (int c = 0; c < 2; ++c) {
            const f32x16& sp = c ? sa1 : sa0;
            #pragma unroll
            for (int s2 = 0; s2 < 2; ++s2) {
                uint32_t a0 = cvtpk_bf16(sp[8*s2+0], sp[8*s2+1]);
                uint32_t a1 = cvtpk_bf16(sp[8*s2+2], sp[8*s2+3]);
                uint32_t b0 = cvtpk_bf16(sp[8*s2+4], sp[8*s2+5]);
                uint32_t b1 = cvtpk_bf16(sp[8*s2+6], sp[8*s2+7]);
                plswap(a0, b0);
                plswap(a1, b1);
                union { uint32_t u[4]; bf16x8 v; } pw;
                pw.u[0] = a0; pw.u[1] = a1; pw.u[2] = b0; pw.u[3] = b1;
                oa0 = __builtin_amdgcn_mfma_f32_32x32x16_bf16(pw.v, vf0[2*c+s2], oa0, 0, 0, 0);
                oa1 = __builtin_amdgcn_mfma_f32_32x32x16_bf16(pw.v, vf1[2*c+s2], oa1, 0, 0, 0);
            }
        }
        __builtin_amdgcn_s_setprio(0);
    }

    // ---- dump partials to LDS (write banks: col%32 distinct, 2-way free)
    {
        float* Ow = &Op[wave][0];
        #pragma unroll
        for (int r = 0; r < 16; ++r) {
            const int row = (r & 3) + 8 * (r >> 2) + hi4;
            Ow[row * 64 + q32]      = oa0[r];
            Ow[row * 64 + 32 + q32] = oa1[r];
        }
        if (hi == 0) Mlw[wave][q32] = make_float2(m_run, l_run);
    }
    __syncthreads();

    // ---- 4-way flash merge: wave w handles rows 8w..8w+7; lane = col
    {
        float* Ob = O + bo + (size_t)(q0 + 32 * qsub) * DK;
        #pragma unroll
        for (int rl = 0; rl < 8; ++rl) {
            const int row = 8 * wave + rl;
            float mg[4], lg[4];
            #pragma unroll
            for (int g = 0; g < 4; ++g) {
                const float2 v = Mlw[g][row];
                mg[g] = v.x; lg[g] = v.y;
            }
            const float mtot = fmaxf(fmaxf(mg[0], mg[1]), fmaxf(mg[2], mg[3]));
            float eg[4], ltot = 0.f;
            #pragma unroll
            for (int g = 0; g < 4; ++g) {
                eg[g] = __builtin_amdgcn_exp2f(mg[g] - mtot);  // MFLOOR -> 0
                ltot += eg[g] * lg[g];
            }
            const float inv = (ltot > 0.f) ? (1.0f / ltot) : 0.f;
            float acc = 0.f;
            #pragma unroll
            for (int g = 0; g < 4; ++g)
                acc += eg[g] * Op[g][row * 64 + lane];
            Ob[(size_t)row * DK + lane] = acc * inv;   // 256B coalesced per row
        }
    }
}

extern "C" void kernel_launch(void* const* d_in, const int* in_sizes, int n_in,
                              void* d_out, int out_size, void* d_ws, size_t ws_size,
                              hipStream_t stream) {
    (void)in_sizes; (void)n_in; (void)out_size; (void)ws_size;
    const float* q = (const float*)d_in[0];
    const float* k = (const float*)d_in[1];
    const float* v = (const float*)d_in[2];
    float* o = (float*)d_out;
    short* wk = (short*)d_ws;                       // 4 MB bf16 K fragments
    short* wv = wk + (size_t)8 * 64 * 4096;         // 4 MB bf16 V^T fragments

    hipLaunchKernelGGL(prep_kernel, dim3(64, 8), dim3(256), 0, stream, k, v, wk, wv);
    hipLaunchKernelGGL(attn_kernel, dim3(64, 16), dim3(256), 0, stream, q, o, wk, wv);
}

// Round 23
// 55.239 us; speedup vs baseline: 2.0926x; 1.0037x over previous
//
#include <hip/hip_runtime.h>
#include <hip/hip_bf16.h>
#include <stdint.h>

#define S_LEN 4096
#define DK    64

typedef __bf16 bf16x8  __attribute__((ext_vector_type(8)));
typedef float  f32x16  __attribute__((ext_vector_type(16)));

__device__ __forceinline__ short f2bf(float f) {
    union { __bf16 h; short s; } u; u.h = (__bf16)f; return u.s;
}

__device__ __forceinline__ uint32_t cvtpk_bf16(float lo, float hi) {
    uint32_t d;
    asm("v_cvt_pk_bf16_f32 %0, %1, %2" : "=&v"(d) : "v"(lo), "v"(hi));
    return d;
}
__device__ __forceinline__ void plswap(uint32_t& a, uint32_t& b) {
    asm("v_permlane32_swap_b32 %0, %1" : "+v"(a), "+v"(b));
}

// ---- prep: fragment-major bf16 layout so a wave's MFMA fragment load is one
// fully-coalesced 1KB global read.
//   K element (row, col=16s+8h+e)  -> WK[((b*64+t)*4+s)*1024 + (row*2+h)*8 + e]
//   V^T element (d, key=16s+8h+e)  -> WV[((b*64+t)*4+s)*1024 + (d*2+h)*8 + e]
__global__ __launch_bounds__(256) void prep_kernel(
    const float* __restrict__ K, const float* __restrict__ V,
    short* __restrict__ WK, short* __restrict__ WV)
{
    const int t = blockIdx.x, b = blockIdx.y;
    const int tid = threadIdx.x;
    const size_t ibase = ((size_t)b * S_LEN + (size_t)t * 64) * DK;
    const size_t obase = ((size_t)b * 64 + t) * 4096;
    const int r0 = tid >> 4;          // 0..15
    const int c0 = (tid & 15) * 4;    // 0..60

    {
        const int s = c0 >> 4, h = (c0 >> 3) & 1, e = c0 & 7;
        #pragma unroll
        for (int i = 0; i < 4; ++i) {
            const int row = r0 + 16 * i;
            const float4 f = *reinterpret_cast<const float4*>(K + ibase + (size_t)row * DK + c0);
            short4 sp;
            sp.x = f2bf(f.x); sp.y = f2bf(f.y); sp.z = f2bf(f.z); sp.w = f2bf(f.w);
            *reinterpret_cast<short4*>(WK + obase + (size_t)s * 1024 + (row * 2 + h) * 8 + e) = sp;
        }
    }
    {
        float4 vf[4];
        #pragma unroll
        for (int j = 0; j < 4; ++j)
            vf[j] = *reinterpret_cast<const float4*>(V + ibase + (size_t)(4 * r0 + j) * DK + c0);
        const int sk = r0 >> 2, hk = (r0 >> 1) & 1, ek = (r0 & 1) * 4;
        #pragma unroll
        for (int jj = 0; jj < 4; ++jj) {
            const int d = c0 + jj;
            short4 sp;
            sp.x = f2bf(reinterpret_cast<const float*>(&vf[0])[jj]);
            sp.y = f2bf(reinterpret_cast<const float*>(&vf[1])[jj]);
            sp.z = f2bf(reinterpret_cast<const float*>(&vf[2])[jj]);
            sp.w = f2bf(reinterpret_cast<const float*>(&vf[3])[jj]);
            *reinterpret_cast<short4*>(WV + obase + (size_t)sk * 1024 + (d * 2 + hk) * 8 + ek) = sp;
        }
    }
}

// ---- main: streaming flash attention with 4-way key-segment split.
// 1024 blocks x 256 threads. The block owns 32 q-rows; its 4 waves stream
// DISJOINT contiguous key-tile segments with ZERO synchronization, then one
// barrier + 4-way flash merge in LDS.
// Per-CU balance (R22 bug fix): co-resident blocks are L, L+256, L+512, L+768
// (round-robin over 256 CUs; 256 = 0 mod 64 made all 4 share one qb before).
// New mapping gives them qb = {63-j, j, 63-j, j} -> exactly 130 wave-tiles
// per CU, constant per-SIMD issue work. Bijective over (qb,batch,qsub).
__global__ __launch_bounds__(256, 2) void attn_kernel(
    const float* __restrict__ Q, float* __restrict__ O,
    const short* __restrict__ WK, const short* __restrict__ WV)
{
    __shared__ float  Op[4][2048];    // per-wave O-partial [row][d], f32
    __shared__ float2 Mlw[4][32];     // per-wave {m,l} per row (log2 domain)

    const int tid  = threadIdx.x;
    const int wave = tid >> 6;
    const int lane = tid & 63;
    const int q32  = lane & 31;
    const int hi   = lane >> 5;
    const int hi4  = hi * 4;
    const int hi8  = hi * 8;

    // balanced job mapping
    const int L  = (int)blockIdx.x + 64 * (int)blockIdx.y;  // 0..1023
    const int c  = L >> 8;          // co-residency chunk 0..3
    const int r  = L & 255;
    const int j  = r & 63;
    const int u  = r >> 6;
    const int bb = c * 4 + u;       // 0..15
    const int batch = bb >> 1;
    const int qsub  = bb & 1;
    const int qb    = (c & 1) ? j : 63 - j;

    const size_t bo = (size_t)batch * S_LEN * DK;
    const short* WKb = WK + (size_t)batch * 262144;
    const short* WVb = WV + (size_t)batch * 262144;

    const int q0   = qb * 64;
    const int qrow = q0 + 32 * qsub + q32;   // this lane's softmax row
    const int idx8 = (q32 * 2 + hi) * 8;     // fragment-major lane offset (shorts)

    const int ntiles = qb + 1;
    const int kt0 = (wave * ntiles) >> 2;        // this wave's segment
    const int kt1 = ((wave + 1) * ntiles) >> 2;

    const float NEG_INF = -__builtin_inff();
    const float MFLOOR  = -1e38f;
    const float QSCALE  = 0.015625f * 1.44269504088896341f;  // 1/64 * log2(e)
    const float THR     = 8.0f;

    // Q fragments (B operand), scale folded
    bf16x8 qf[4];
    {
        const float* Qr = Q + bo + (size_t)qrow * DK;
        #pragma unroll
        for (int s = 0; s < 4; ++s) {
            const float4 a = *reinterpret_cast<const float4*>(Qr + 16 * s + hi8);
            const float4 b = *reinterpret_cast<const float4*>(Qr + 16 * s + hi8 + 4);
            qf[s][0] = (__bf16)(a.x * QSCALE); qf[s][1] = (__bf16)(a.y * QSCALE);
            qf[s][2] = (__bf16)(a.z * QSCALE); qf[s][3] = (__bf16)(a.w * QSCALE);
            qf[s][4] = (__bf16)(b.x * QSCALE); qf[s][5] = (__bf16)(b.y * QSCALE);
            qf[s][6] = (__bf16)(b.z * QSCALE); qf[s][7] = (__bf16)(b.w * QSCALE);
        }
    }

    float m_run = MFLOOR, l_run = 0.f;
    f32x16 oa0, oa1;  // O-partial[q=crow(r,hi)][d = q32 / 32+q32]
    #pragma unroll
    for (int r2 = 0; r2 < 16; ++r2) { oa0[r2] = 0.f; oa1[r2] = 0.f; }

    for (int kt = kt0; kt < kt1; ++kt) {
        const short* Kt = WKb + (size_t)kt * 4096;
        const short* Vt = WVb + (size_t)kt * 4096;

        // 16 coalesced fragment loads; compiler overlaps V arrival with QK^T.
        bf16x8 kf0[4], kf1[4], vf0[4], vf1[4];
        #pragma unroll
        for (int s = 0; s < 4; ++s) {
            kf0[s] = *reinterpret_cast<const bf16x8*>(Kt + s * 1024 + idx8);
            kf1[s] = *reinterpret_cast<const bf16x8*>(Kt + s * 1024 + 512 + idx8);
        }
        #pragma unroll
        for (int s = 0; s < 4; ++s) {
            vf0[s] = *reinterpret_cast<const bf16x8*>(Vt + s * 1024 + idx8);
            vf1[s] = *reinterpret_cast<const bf16x8*>(Vt + s * 1024 + 512 + idx8);
        }

        // ---- S^T = K Q (swapped): lane owns full row q32
        f32x16 sa0, sa1;
        #pragma unroll
        for (int r2 = 0; r2 < 16; ++r2) { sa0[r2] = 0.f; sa1[r2] = 0.f; }
        __builtin_amdgcn_s_setprio(1);
        #pragma unroll
        for (int s = 0; s < 4; ++s) {
            sa0 = __builtin_amdgcn_mfma_f32_32x32x16_bf16(kf0[s], qf[s], sa0, 0, 0, 0);
            sa1 = __builtin_amdgcn_mfma_f32_32x32x16_bf16(kf1[s], qf[s], sa1, 0, 0, 0);
        }
        __builtin_amdgcn_s_setprio(0);

        // ---- causal mask (diag tile only; uniform branch) + row max
        float ma[4] = {NEG_INF, NEG_INF, NEG_INF, NEG_INF};
        if (kt == qb) {
            const int keybase = kt * 64 + hi4;
            #pragma unroll
            for (int r2 = 0; r2 < 16; ++r2) {
                const int kl = (r2 & 3) + 8 * (r2 >> 2);
                if (keybase + kl > qrow) sa0[r2] = NEG_INF;
                ma[r2 & 3] = fmaxf(ma[r2 & 3], sa0[r2]);
                if (keybase + kl + 32 > qrow) sa1[r2] = NEG_INF;
                ma[r2 & 3] = fmaxf(ma[r2 & 3], sa1[r2]);
            }
        } else {
            #pragma unroll
            for (int r2 = 0; r2 < 16; ++r2) {
                ma[r2 & 3] = fmaxf(ma[r2 & 3], sa0[r2]);
                ma[r2 & 3] = fmaxf(ma[r2 & 3], sa1[r2]);
            }
        }
        float mt = fmaxf(fmaxf(ma[0], ma[1]), fmaxf(ma[2], ma[3]));
        mt = fmaxf(mt, __shfl_xor(mt, 32));

        // ---- T13: rescale only when max grew past THR (first tile fires;
        // alpha underflows to 0 from MFLOOR, establishing finite m_run)
        if (!__all(mt <= m_run + THR)) {
            const float mnew = fmaxf(m_run, mt);
            const float alpha = __builtin_amdgcn_exp2f(m_run - mnew);
            m_run = mnew;
            l_run *= alpha;
            #pragma unroll
            for (int r2 = 0; r2 < 16; ++r2) {
                const float ar = __shfl(alpha, (r2 & 3) + 8 * (r2 >> 2) + hi4);
                oa0[r2] *= ar; oa1[r2] *= ar;
            }
        }

        // ---- exp2 + row sum (4-way partials); P bounded by 2^THR
        float pp[4] = {0.f, 0.f, 0.f, 0.f};
        #pragma unroll
        for (int r2 = 0; r2 < 16; ++r2) {
            sa0[r2] = __builtin_amdgcn_exp2f(sa0[r2] - m_run); pp[r2 & 3] += sa0[r2];
            sa1[r2] = __builtin_amdgcn_exp2f(sa1[r2] - m_run); pp[r2 & 3] += sa1[r2];
        }
        float ps = (pp[0] + pp[1]) + (pp[2] + pp[3]);
        ps += __shfl_xor(ps, 32);
        l_run += ps;

        // ---- PV with in-register P (T12)
        __builtin_amdgcn_s_setprio(1);
        #pragma unroll
        for (int cc = 0; cc < 2; ++cc) {
            const f32x16& sp = cc ? sa1 : sa0;
            #pragma unroll
            for (int s2 = 0; s2 < 2; ++s2) {
                uint32_t a0 = cvtpk_bf16(sp[8*s2+0], sp[8*s2+1]);
                uint32_t a1 = cvtpk_bf16(sp[8*s2+2], sp[8*s2+3]);
                uint32_t b0 = cvtpk_bf16(sp[8*s2+4], sp[8*s2+5]);
                uint32_t b1 = cvtpk_bf16(sp[8*s2+6], sp[8*s2+7]);
                plswap(a0, b0);
                plswap(a1, b1);
                union { uint32_t u[4]; bf16x8 v; } pw;
                pw.u[0] = a0; pw.u[1] = a1; pw.u[2] = b0; pw.u[3] = b1;
                oa0 = __builtin_amdgcn_mfma_f32_32x32x16_bf16(pw.v, vf0[2*cc+s2], oa0, 0, 0, 0);
                oa1 = __builtin_amdgcn_mfma_f32_32x32x16_bf16(pw.v, vf1[2*cc+s2], oa1, 0, 0, 0);
            }
        }
        __builtin_amdgcn_s_setprio(0);
    }

    // ---- dump partials to LDS (write banks: col%32 distinct, 2-way free)
    {
        float* Ow = &Op[wave][0];
        #pragma unroll
        for (int r2 = 0; r2 < 16; ++r2) {
            const int row = (r2 & 3) + 8 * (r2 >> 2) + hi4;
            Ow[row * 64 + q32]      = oa0[r2];
            Ow[row * 64 + 32 + q32] = oa1[r2];
        }
        if (hi == 0) Mlw[wave][q32] = make_float2(m_run, l_run);
    }
    __syncthreads();

    // ---- 4-way flash merge: wave w handles rows 8w..8w+7; lane = col
    {
        float* Ob = O + bo + (size_t)(q0 + 32 * qsub) * DK;
        #pragma unroll
        for (int rl = 0; rl < 8; ++rl) {
            const int row = 8 * wave + rl;
            float mg[4], lg[4];
            #pragma unroll
            for (int g = 0; g < 4; ++g) {
                const float2 v = Mlw[g][row];
                mg[g] = v.x; lg[g] = v.y;
            }
            const float mtot = fmaxf(fmaxf(mg[0], mg[1]), fmaxf(mg[2], mg[3]));
            float eg[4], ltot = 0.f;
            #pragma unroll
            for (int g = 0; g < 4; ++g) {
                eg[g] = __builtin_amdgcn_exp2f(mg[g] - mtot);  // MFLOOR -> 0
                ltot += eg[g] * lg[g];
            }
            const float inv = (ltot > 0.f) ? (1.0f / ltot) : 0.f;
            float acc = 0.f;
            #pragma unroll
            for (int g = 0; g < 4; ++g)
                acc += eg[g] * Op[g][row * 64 + lane];
            Ob[(size_t)row * DK + lane] = acc * inv;   // 256B coalesced per row
        }
    }
}

extern "C" void kernel_launch(void* const* d_in, const int* in_sizes, int n_in,
                              void* d_out, int out_size, void* d_ws, size_t ws_size,
                              hipStream_t stream) {
    (void)in_sizes; (void)n_in; (void)out_size; (void)ws_size;
    const float* q = (const float*)d_in[0];
    const float* k = (const float*)d_in[1];
    const float* v = (const float*)d_in[2];
    float* o = (float*)d_out;
    short* wk = (short*)d_ws;                       // 4 MB bf16 K fragments
    short* wv = wk + (size_t)8 * 64 * 4096;         // 4 MB bf16 V^T fragments

    hipLaunchKernelGGL(prep_kernel, dim3(64, 8), dim3(256), 0, stream, k, v, wk, wv);
    hipLaunchKernelGGL(attn_kernel, dim3(64, 16), dim3(256), 0, stream, q, o, wk, wv);
}